// Round 18
// baseline (119.118 us; speedup 1.0000x reference)
//
#include <hip/hip_runtime.h>

#define DEV __device__ __forceinline__

typedef __attribute__((ext_vector_type(8))) __bf16 bf16x8;
typedef __attribute__((ext_vector_type(4))) float f32x4;
typedef __attribute__((ext_vector_type(16))) float f32x16;
typedef __attribute__((ext_vector_type(4))) unsigned short u16x4;
typedef __attribute__((ext_vector_type(8))) unsigned short u16x8;
typedef __attribute__((ext_vector_type(2))) unsigned u32x2;

// RNE float -> bf16 bits
DEV unsigned short f2bf(float f) {
  unsigned u = __builtin_bit_cast(unsigned, f);
  u += 0x7FFFu + ((u >> 16) & 1u);
  return (unsigned short)(u >> 16);
}

DEV f32x4 mfma16(bf16x8 a, bf16x8 b, f32x4 c) {
  return __builtin_amdgcn_mfma_f32_16x16x32_bf16(a, b, c, 0, 0, 0);
}
DEV f32x16 mfma32(bf16x8 a, bf16x8 b, f32x16 c) {
  return __builtin_amdgcn_mfma_f32_32x32x16_bf16(a, b, c, 0, 0, 0);
}

// async global->LDS, 16B per lane; LDS dest must be wave-uniform base + lane*16
DEV void gload16(const void* g, void* l) {
  __builtin_amdgcn_global_load_lds(
      (const __attribute__((address_space(1))) unsigned int*)g,
      (__attribute__((address_space(3))) unsigned int*)l, 16, 0, 0);
}

// v_permlane32_swap_b32 (T12 primitive); semantics validated in R5/R6.
DEV void plswap(unsigned& x, unsigned& y) {
#if __has_builtin(__builtin_amdgcn_permlane32_swap)
  u32x2 r = __builtin_amdgcn_permlane32_swap(x, y, false, false);
  x = r[0];
  y = r[1];
#else
  unsigned sx = __shfl_xor(x, 32, 64), sy = __shfl_xor(y, 32, 64);
  int hi = (threadIdx.x & 63) >> 5;
  unsigned nx = hi ? sy : x;
  unsigned ny = hi ? y : sx;
  x = nx;
  y = ny;
#endif
}
DEV float xadd32(float v) {
  unsigned a = __builtin_bit_cast(unsigned, v), b = a;
  plswap(a, b);
  return __builtin_bit_cast(float, a) + __builtin_bit_cast(float, b);
}

// ---------------------------------------------------------------------------
// Fused fp32 -> bf16 swizzled convert for x + 4 weight matrices.
// ---------------------------------------------------------------------------
__global__ __launch_bounds__(256) void k_cvt_all(
    const float* __restrict__ x,
    const float* __restrict__ Wq, const float* __restrict__ Wk,
    const float* __restrict__ Wv, const float* __restrict__ Wo,
    unsigned short* __restrict__ xb,
    unsigned short* __restrict__ Wqb, unsigned short* __restrict__ Wkb,
    unsigned short* __restrict__ Wvb, unsigned short* __restrict__ Wob) {
  int g = blockIdx.x * 256 + threadIdx.x;
  const float* src;
  unsigned short* dst;
  int loc;
  if (g < 524288) {
    src = x; dst = xb; loc = g;
  } else {
    int r = g - 524288;
    int w = r >> 17;
    loc = r & 131071;
    src = w == 0 ? Wq : w == 1 ? Wk : w == 2 ? Wv : Wo;
    dst = w == 0 ? Wqb : w == 1 ? Wkb : w == 2 ? Wvb : Wob;
  }
  int row = loc >> 7, k8 = loc & 127;
  const f32x4* s = (const f32x4*)(src + ((size_t)row << 10) + (k8 << 3));
  f32x4 a = s[0], b = s[1];
  u16x8 o;
  o[0] = f2bf(a[0]); o[1] = f2bf(a[1]); o[2] = f2bf(a[2]); o[3] = f2bf(a[3]);
  o[4] = f2bf(b[0]); o[5] = f2bf(b[1]); o[6] = f2bf(b[2]); o[7] = f2bf(b[3]);
  *(u16x8*)(dst + ((size_t)row << 10) + ((k8 << 3) ^ ((row & 7) << 3))) = o;
}

// ---------------------------------------------------------------------------
// NT-GEMM mainloop: dbuf + counted vmcnt (validated R15).
// ---------------------------------------------------------------------------
DEV void gemm_mainloop(const char* Ag, const char* Bg, char* lds,
                       int lane, int wid, f32x4 acc[4][4]) {
  int g4 = lane >> 4, r16 = lane & 15;
  int wm = wid >> 1, wn = wid & 1;
  int adA[2], adB[2];
#pragma unroll
  for (int ks = 0; ks < 2; ++ks) {
    int swz = ((ks * 4 + g4) ^ (lane & 7)) << 4;
    adA[ks] = (wm * 64 + r16) * 128 + swz;
    adB[ks] = 16384 + (wn * 64 + r16) * 128 + swz;
  }
  int o0 = wid * 4096 + lane * 16;
  int grow[4], ginr[4];
#pragma unroll
  for (int i = 0; i < 4; ++i) {
    grow[i] = (o0 + i * 1024) >> 7;
    ginr[i] = (o0 + i * 1024) & 127;
  }
  auto STAGE = [&](int KT, int BASE) {
#pragma unroll
    for (int i = 0; i < 4; ++i) {
      int oo = o0 + i * 1024;
      size_t gofs = (size_t)grow[i] * 2048 + (size_t)KT * 128 + ginr[i];
      gload16(Ag + gofs, lds + BASE + oo);
      gload16(Bg + gofs, lds + BASE + 16384 + oo);
    }
  };
  STAGE(0, 0);
  for (int kt = 0; kt < 16; ++kt) {
    int cur = (kt & 1) << 15;
    if (kt + 1 < 16) {
      STAGE(kt + 1, cur ^ 32768);                      // flies across barrier
      asm volatile("s_waitcnt vmcnt(8)" ::: "memory"); // tile-kt landed
    } else {
      asm volatile("s_waitcnt vmcnt(0)" ::: "memory");
    }
    __builtin_amdgcn_s_barrier();       // all waves' tile-kt loads landed
    __builtin_amdgcn_sched_barrier(0);  // no hoist of ds_read above (rule 18)
#pragma unroll
    for (int ks = 0; ks < 2; ++ks) {
      bf16x8 af[4], bfr[4];
#pragma unroll
      for (int i = 0; i < 4; ++i) {
        af[i]  = *(const bf16x8*)(lds + cur + adA[ks] + i * 2048);
        bfr[i] = *(const bf16x8*)(lds + cur + adB[ks] + i * 2048);
      }
      __builtin_amdgcn_s_setprio(1);
#pragma unroll
      for (int mi = 0; mi < 4; ++mi)
#pragma unroll
        for (int ni = 0; ni < 4; ++ni)
          acc[mi][ni] = mfma16(af[mi], bfr[ni], acc[mi][ni]);
      __builtin_amdgcn_s_setprio(0);
    }
    asm volatile("s_waitcnt lgkmcnt(0)" ::: "memory");  // ds_reads drained
    __builtin_amdgcn_sched_barrier(0);
    __builtin_amdgcn_s_barrier();       // safe to overwrite other buf next iter
  }
}

// ---------------------------------------------------------------------------
// QKV projection: Q,K row-major [bh][s][64]; V transposed [bh][hd][s].
// Q is PRE-SCALED by 0.125*log2(e) so attention computes exp2(s) directly.
// ---------------------------------------------------------------------------
__global__ __launch_bounds__(256) void k_gemm_qkv(
    const unsigned short* __restrict__ xb,
    const unsigned short* __restrict__ Wqb, const unsigned short* __restrict__ Wkb,
    const unsigned short* __restrict__ Wvb,
    const float* __restrict__ bq, const float* __restrict__ bk,
    const float* __restrict__ bv,
    unsigned short* __restrict__ Qb, unsigned short* __restrict__ Kb,
    unsigned short* __restrict__ Vt) {
  __shared__ char lds[65536];
  int tid = threadIdx.x, lane = tid & 63, wid = tid >> 6;
  int bm = blockIdx.x & 31, bn = blockIdx.x >> 5;
  int r0 = bm * 128;
  int colT = bn * 128;
  int which = colT >> 10;
  int ncol = colT & 1023;
  const unsigned short* Wb = which == 0 ? Wqb : which == 1 ? Wkb : Wvb;
  f32x4 acc[4][4] = {};
  gemm_mainloop((const char*)xb + (size_t)r0 * 2048,
                (const char*)Wb + (size_t)ncol * 2048, lds, lane, wid, acc);
  int g4 = lane >> 4, r16 = lane & 15, wm = wid >> 1, wn = wid & 1;
  const float* bias = which == 0 ? bq : which == 1 ? bk : bv;
  float oscale = which == 0 ? 0.18033688f : 1.0f;  // Q pre-scale: 0.125*log2e
  int ncolw = ncol + wn * 64;
#pragma unroll
  for (int ni = 0; ni < 4; ++ni) {
    int gcol = ncolw + ni * 16 + r16;
    float bvv = bias[gcol];
    int h = gcol >> 6, hd = gcol & 63;
#pragma unroll
    for (int mi = 0; mi < 4; ++mi) {
      int growb = r0 + wm * 64 + mi * 16 + g4 * 4;
      int bb = growb >> 11, s0 = growb & 2047;
      if (which == 2) {
        u16x4 pk;
#pragma unroll
        for (int jj = 0; jj < 4; ++jj) pk[jj] = f2bf(acc[mi][ni][jj] + bvv);
        *(u16x4*)(Vt + ((size_t)(bb * 16 + h) * 64 + hd) * 2048 + s0) = pk;
      } else {
        unsigned short* dst = which == 0 ? Qb : Kb;
        size_t base = ((size_t)(bb * 16 + h) * 2048 + s0) * 64 + hd;
#pragma unroll
        for (int jj = 0; jj < 4; ++jj)
          dst[base + (size_t)jj * 64] = f2bf((acc[mi][ni][jj] + bvv) * oscale);
      }
    }
  }
}

// ---------------------------------------------------------------------------
// Flash attention, causal — R16 dbuf/counted-vmcnt structure with 64 q-rows
// PER WAVE (2 serialized q-groups of 32). Block = 2 waves = 128-row chunk;
// 16 chunks; KVBLK=64; LDS 32KB dbuf unchanged. Halves wave-iterations per
// kv element and halves K/V fetch per q-row (per-iteration overhead is the
// measured binding constant, R16 vs R17). Split-K: nt=2c+2 tiles, nseg=
// ceil(nt/8), 40 segments/bh, strictly descending length dispatch.
// No-max softmax (Q pre-scaled); plain-add combine.
// ---------------------------------------------------------------------------
__global__ __launch_bounds__(128) void k_attn(
    const unsigned short* __restrict__ Q, const unsigned short* __restrict__ K,
    const unsigned short* __restrict__ Vt, unsigned short* __restrict__ ansb,
    float* __restrict__ PO, float* __restrict__ PL) {
  __shared__ char lds[2 * 16384];
  // entry: c | t0<<8 | t1<<16 | j<<24, strictly descending (t1-t0)
#define SG(c, a, bb2, jj) \
  ((unsigned)(c) | ((unsigned)(a) << 8) | ((unsigned)(bb2) << 16) | ((unsigned)(jj) << 24))
  static const unsigned SEGT[40] = {
    // len 8 (13)
    SG(3,0,8,0),  SG(7,0,8,0),  SG(7,8,16,1),  SG(10,14,22,2),
    SG(11,0,8,0), SG(11,8,16,1), SG(11,16,24,2),
    SG(14,7,15,1), SG(14,22,30,3),
    SG(15,0,8,0), SG(15,8,16,1), SG(15,16,24,2), SG(15,24,32,3),
    // len 7 (14)
    SG(6,0,7,0),  SG(6,7,14,1),  SG(9,6,13,1),  SG(9,13,20,2),
    SG(10,0,7,0), SG(10,7,14,1), SG(12,6,13,1), SG(12,19,26,3),
    SG(13,0,7,0), SG(13,7,14,1), SG(13,14,21,2), SG(13,21,28,3),
    SG(14,0,7,0), SG(14,15,22,2),
    // len 6 (9)
    SG(2,0,6,0),  SG(5,0,6,0),  SG(5,6,12,1),
    SG(8,0,6,0),  SG(8,6,12,1), SG(8,12,18,2),
    SG(9,0,6,0),  SG(12,0,6,0), SG(12,13,19,2),
    // len 5 (2)
    SG(4,0,5,0),  SG(4,5,10,1),
    // tails
    SG(1,0,4,0),  SG(0,0,2,0)
  };
#undef SG
  int tid = threadIdx.x, lane = tid & 63, wid = tid >> 6;  // wid 0..1
  int l31 = lane & 31, hi = lane >> 5;
  int bid = blockIdx.x;
  int bh = (bid & 7) * 4 + ((bid >> 3) & 3);  // same bh -> same XCD (mod-8 rr)
  unsigned se = SEGT[bid >> 5];
  int c = se & 255, t0 = (se >> 8) & 255, t1 = (se >> 16) & 255, j = se >> 24;
  bool direct = (c < 4);                       // nseg==1 chunks
  int pidx = (bh * 12 + (c - 4)) * 4 + j;      // valid only when !direct
  int b = bh >> 4, h = bh & 15;
  int q0 = c * 128 + wid * 64;      // this wave's q-row base (64 rows)
  const unsigned short* Qh = Q + (size_t)bh * (2048 * 64);
  const char* Kg = (const char*)(K + (size_t)bh * (2048 * 64));
  const char* Vg = (const char*)(Vt + (size_t)bh * (64 * 2048));

  // staging offsets (128 threads, 8KB K + 8KB V -> 4+4 gload16 per thread)
  int kof[4], ko[4], vo[4];
#pragma unroll
  for (int i = 0; i < 4; ++i) {
    int o = tid * 16 + i * 2048;
    int row = o >> 7, cc = o & 127;
    int sc = cc ^ ((row & 7) << 4);
    kof[i] = o;
    ko[i] = row * 128 + sc;    // K rows = kv (row stride 128B)
    vo[i] = row * 4096 + sc;   // V rows = hd (row stride 4096B)
  }

  // Q fragments (B-operand), 2 groups of 32 q-rows
  bf16x8 qf[2][4];
#pragma unroll
  for (int qg = 0; qg < 2; ++qg)
#pragma unroll
    for (int ks = 0; ks < 4; ++ks)
      qf[qg][ks] = *(const bf16x8*)(Qh + (size_t)(q0 + qg * 32 + l31) * 64 +
                                    ks * 16 + hi * 8);

  f32x16 O[2][2] = {};   // [qg][d-half]
  f32x16 lac[2] = {};
  int swzl = (l31 & 7) << 4;
  int hioff = hi * 16;

  auto STAGEA = [&](int T, int BASE) {
    size_t kK = (size_t)T * 8192;   // K tile byte offset (64 rows x 128B)
    size_t kV = (size_t)T * 128;    // V tile byte offset (64 kv x 2B per row)
#pragma unroll
    for (int i = 0; i < 4; ++i) {
      gload16(Kg + kK + ko[i], lds + BASE + kof[i]);
      gload16(Vg + kV + vo[i], lds + BASE + 8192 + kof[i]);
    }
  };

  STAGEA(t0, 0);
  for (int t = t0; t < t1; ++t) {
    int cur = ((t - t0) & 1) << 14;
    if (t + 1 < t1) {
      STAGEA(t + 1, cur ^ 16384);                       // flies across barrier
      asm volatile("s_waitcnt vmcnt(8)" ::: "memory");  // tile-t landed
    } else {
      asm volatile("s_waitcnt vmcnt(0)" ::: "memory");
    }
    __builtin_amdgcn_s_barrier();        // all waves' tile-t loads landed
    __builtin_amdgcn_sched_barrier(0);   // no hoist of ds_read above (rule 18)
    const char* KL = lds + cur;
    const char* VL = KL + 8192;
#pragma unroll
    for (int qg = 0; qg < 2; ++qg) {   // serialized q-groups: s stays 32 VGPR
      f32x16 s0 = {}, s1 = {};
      __builtin_amdgcn_s_setprio(1);
#pragma unroll
      for (int ks = 0; ks < 4; ++ks) {
        bf16x8 kf0 = *(const bf16x8*)(KL + l31 * 128 + ((ks * 32 + hioff) ^ swzl));
        bf16x8 kf1 = *(const bf16x8*)(KL + (32 + l31) * 128 + ((ks * 32 + hioff) ^ swzl));
        s0 = mfma32(kf0, qf[qg][ks], s0);
        s1 = mfma32(kf1, qf[qg][ks], s1);
      }
      __builtin_amdgcn_s_setprio(0);
      int qgb = q0 + qg * 32;
      if (t * 64 + 63 > qgb) {  // tile crosses/exceeds this group's diagonal
        int lim2 = qgb + l31 - t * 64 - 4 * hi;
#pragma unroll
        for (int r = 0; r < 16; ++r) {
          int kc = (r & 3) + 8 * (r >> 2);
          if (kc > lim2) s0[r] = -1e30f;
          if (kc + 32 > lim2) s1[r] = -1e30f;
        }
      }
      // P = exp2(s) (Q pre-scaled; masked -1e30 -> 0); per-lane partial l
#pragma unroll
      for (int r = 0; r < 16; ++r) {
        s0[r] = __builtin_amdgcn_exp2f(s0[r]);
        s1[r] = __builtin_amdgcn_exp2f(s1[r]);
        lac[qg][r] += s0[r] + s1[r];
      }
      // pack P->bf16 A-frags: cvt_pk pairs + permlane32_swap
      __builtin_amdgcn_s_setprio(1);
#define PV_CHUNK(SV, E, C16) { \
      unsigned x0, x1, y0, y1; \
      asm("v_cvt_pk_bf16_f32 %0, %1, %2" : "=v"(x0) : "v"(SV[8*(E)+0]), "v"(SV[8*(E)+1])); \
      asm("v_cvt_pk_bf16_f32 %0, %1, %2" : "=v"(x1) : "v"(SV[8*(E)+2]), "v"(SV[8*(E)+3])); \
      asm("v_cvt_pk_bf16_f32 %0, %1, %2" : "=v"(y0) : "v"(SV[8*(E)+4]), "v"(SV[8*(E)+5])); \
      asm("v_cvt_pk_bf16_f32 %0, %1, %2" : "=v"(y1) : "v"(SV[8*(E)+6]), "v"(SV[8*(E)+7])); \
      plswap(x0, y0); \
      plswap(x1, y1); \
      union { unsigned u[4]; bf16x8 v; } pf; \
      pf.u[0] = x0; \
      pf.u[1] = x1; \
      pf.u[2] = y0; \
      pf.u[3] = y1; \
      bf16x8 v0 = *(const bf16x8*)(VL + l31 * 128 + (((C16) * 32 + hioff) ^ swzl)); \
      bf16x8 v1 = *(const bf16x8*)(VL + (32 + l31) * 128 + (((C16) * 32 + hioff) ^ swzl)); \
      O[qg][0] = mfma32(pf.v, v0, O[qg][0]); \
      O[qg][1] = mfma32(pf.v, v1, O[qg][1]); }
      PV_CHUNK(s0, 0, 0)
      PV_CHUNK(s0, 1, 1)
      PV_CHUNK(s1, 0, 2)
      PV_CHUNK(s1, 1, 3)
#undef PV_CHUNK
      __builtin_amdgcn_s_setprio(0);
    }
    asm volatile("s_waitcnt lgkmcnt(0)" ::: "memory");  // my ds_reads drained
    __builtin_amdgcn_sched_barrier(0);
    __builtin_amdgcn_s_barrier();   // all waves done reading buf before reuse
  }
  // per-group row-sum of l -> lf[qg] (per-lane for its q-row l31)
  float lf[2];
#pragma unroll
  for (int qg = 0; qg < 2; ++qg) {
    float a[16];
#pragma unroll
    for (int r = 0; r < 16; ++r) a[r] = lac[qg][r];
#pragma unroll
    for (int st2 = 8; st2 >= 1; st2 >>= 1)
#pragma unroll
      for (int i = 0; i < st2; ++i) a[i] += a[i + st2];
    lf[qg] = xadd32(a[0]);
  }
  __syncthreads();  // K/V buffers dead on all waves; strip reuse safe
  char* wb = lds + wid * 256;  // per-wave 64-row strip (reuses buffer 0)
  if (direct) {
#pragma unroll
    for (int qg = 0; qg < 2; ++qg)
      if (lane < 32) *(float*)(wb + qg * 128 + l31 * 4) = 1.f / lf[qg];
    asm volatile("s_waitcnt lgkmcnt(0)" ::: "memory");
#pragma unroll
    for (int qg = 0; qg < 2; ++qg) {
      f32x4 rv0 = *(const f32x4*)(wb + qg * 128 + hioff);
      f32x4 rv1 = *(const f32x4*)(wb + qg * 128 + 32 + hioff);
      f32x4 rv2 = *(const f32x4*)(wb + qg * 128 + 64 + hioff);
      f32x4 rv3 = *(const f32x4*)(wb + qg * 128 + 96 + hioff);
#pragma unroll
      for (int r = 0; r < 16; ++r) {
        float sc = (r < 4 ? rv0 : r < 8 ? rv1 : r < 12 ? rv2 : rv3)[r & 3];
        int rowl = q0 + qg * 32 + (r & 3) + 8 * (r >> 2) + 4 * hi;
        int rowg = (b << 11) + rowl;
        int cswz = (rowl & 7) << 3;
        int cg0 = (h << 6) + l31;
        int cg1 = (h << 6) + 32 + l31;
        ansb[(size_t)rowg * 1024 + (cg0 ^ cswz)] = f2bf(O[qg][0][r] * sc);
        ansb[(size_t)rowg * 1024 + (cg1 ^ cswz)] = f2bf(O[qg][1][r] * sc);
      }
    }
  } else {
    float* po = PO + (size_t)pidx * 8192;   // [128 rows][64] f32
#pragma unroll
    for (int qg = 0; qg < 2; ++qg) {
#pragma unroll
      for (int r = 0; r < 16; ++r) {
        int rowl = wid * 64 + qg * 32 + (r & 3) + 8 * (r >> 2) + 4 * hi;
        po[rowl * 64 + l31] = O[qg][0][r];
        po[rowl * 64 + 32 + l31] = O[qg][1][r];
      }
      if (hi == 0) PL[pidx * 128 + wid * 64 + qg * 32 + l31] = lf[qg];
    }
  }
}

// ---------------------------------------------------------------------------
// Split-K combine: for (bh, chunk 4..15 of 128 rows) sum nseg partials,
// normalize, write swizzled bf16 ansb. Grid 768 = 32 bh x 12 chunks x 2
// half-blocks; 256 thr (thread t -> row 64*sub + (t>>2), cols (t&3)*16..).
// ---------------------------------------------------------------------------
__global__ __launch_bounds__(256) void k_attn_combine(
    const float* __restrict__ PO, const float* __restrict__ PL,
    unsigned short* __restrict__ ansb) {
  int bid = blockIdx.x;
  int bh = bid & 31, rest = bid >> 5;          // 0..23
  int cc = 4 + (rest >> 1), sub = rest & 1;
  int nseg = cc < 8 ? 2 : cc < 12 ? 3 : 4;
  int b = bh >> 4, h = bh & 15;
  int t = threadIdx.x;
  int r = sub * 64 + (t >> 2), c4 = (t & 3) << 4;
  int pbase = (bh * 12 + (cc - 4)) * 4;
  f32x4 s0 = {}, s1 = {}, s2 = {}, s3 = {};
  float lsum = 0.f;
  for (int j = 0; j < nseg; ++j) {
    const float* A = PO + (size_t)(pbase + j) * 8192 + r * 64 + c4;
    s0 += *(const f32x4*)(A + 0);
    s1 += *(const f32x4*)(A + 4);
    s2 += *(const f32x4*)(A + 8);
    s3 += *(const f32x4*)(A + 12);
    lsum += PL[(pbase + j) * 128 + r];
  }
  float rl = 1.f / lsum;
  u16x8 o0, o1;
#pragma unroll
  for (int j = 0; j < 4; ++j) {
    o0[j] = f2bf(s0[j] * rl);
    o0[4 + j] = f2bf(s1[j] * rl);
    o1[j] = f2bf(s2[j] * rl);
    o1[4 + j] = f2bf(s3[j] * rl);
  }
  int rowg = (b << 11) + cc * 128 + r;
  int colg = (h << 6) + c4;
  int cswz = (rowg & 7) << 3;
  *(u16x8*)(ansb + (size_t)rowg * 1024 + (colg ^ cswz)) = o0;
  *(u16x8*)(ansb + (size_t)rowg * 1024 + ((colg + 8) ^ cswz)) = o1;
}

// ---------------------------------------------------------------------------
// Output projection: out(fp32) = ansb(swz) * Wo^T + bo. Grid 256.
// ---------------------------------------------------------------------------
__global__ __launch_bounds__(256) void k_gemm_out(
    const unsigned short* __restrict__ ansb, const unsigned short* __restrict__ Wob,
    const float* __restrict__ bo, float* __restrict__ out) {
  __shared__ char lds[65536];
  int tid = threadIdx.x, lane = tid & 63, wid = tid >> 6;
  int bm = blockIdx.x & 31, bn = blockIdx.x >> 5;
  int r0 = bm * 128, c0 = bn * 128;
  f32x4 acc[4][4] = {};
  gemm_mainloop((const char*)ansb + (size_t)r0 * 2048,
                (const char*)Wob + (size_t)c0 * 2048, lds, lane, wid, acc);
  int g4 = lane >> 4, r16 = lane & 15, wm = wid >> 1, wn = wid & 1;
#pragma unroll
  for (int ni = 0; ni < 4; ++ni) {
    int gcol = c0 + wn * 64 + ni * 16 + r16;
    float bvv = bo[gcol];
#pragma unroll
    for (int mi = 0; mi < 4; ++mi) {
      int growb = r0 + wm * 64 + mi * 16 + g4 * 4;
#pragma unroll
      for (int jj = 0; jj < 4; ++jj)
        out[(size_t)(growb + jj) * 1024 + gcol] = acc[mi][ni][jj] + bvv;
    }
  }
}

extern "C" void kernel_launch(void* const* d_in, const int* in_sizes, int n_in,
                              void* d_out, int out_size, void* d_ws, size_t ws_size,
                              hipStream_t stream) {
  const float* x  = (const float*)d_in[0];
  const float* Wq = (const float*)d_in[1];
  const float* bq = (const float*)d_in[2];
  const float* Wk = (const float*)d_in[3];
  const float* bk = (const float*)d_in[4];
  const float* Wv = (const float*)d_in[5];
  const float* bv = (const float*)d_in[6];
  const float* Wo = (const float*)d_in[7];
  const float* bo = (const float*)d_in[8];
  char* ws = (char*)d_ws;
  unsigned short* xb   = (unsigned short*)(ws);                  // 8 MB
  unsigned short* ansb = (unsigned short*)(ws);                  // 8 MB (alias, xb dead)
  unsigned short* Wqb  = (unsigned short*)(ws + (8u  << 20));
  unsigned short* Wkb  = (unsigned short*)(ws + (10u << 20));
  unsigned short* Wvb  = (unsigned short*)(ws + (12u << 20));
  unsigned short* Wob  = (unsigned short*)(ws + (14u << 20));
  unsigned short* Qb   = (unsigned short*)(ws + (16u << 20));
  unsigned short* Kb   = (unsigned short*)(ws + (24u << 20));
  unsigned short* Vt   = (unsigned short*)(ws + (32u << 20));
  float*          PO   = (float*)(ws + (40u << 20));             // 48 MB (1536 x 32KB)
  float*          PL   = (float*)(ws + (88u << 20));             // 768 KB

  k_cvt_all<<<4096, 256, 0, stream>>>(x, Wq, Wk, Wv, Wo, xb, Wqb, Wkb, Wvb, Wob);
  k_gemm_qkv<<<768, 256, 0, stream>>>(xb, Wqb, Wkb, Wvb, bq, bk, bv, Qb, Kb, Vt);
  k_attn<<<1280, 128, 0, stream>>>(Qb, Kb, Vt, ansb, PO, PL);
  k_attn_combine<<<768, 256, 0, stream>>>(PO, PL, ansb);
  k_gemm_out<<<256, 256, 0, stream>>>(ansb, Wob, bo, (float*)d_out);
}

// Round 19
// 102.104 us; speedup vs baseline: 1.1666x; 1.1666x over previous
//
#include <hip/hip_runtime.h>

#define DEV __device__ __forceinline__

typedef __attribute__((ext_vector_type(8))) __bf16 bf16x8;
typedef __attribute__((ext_vector_type(4))) float f32x4;
typedef __attribute__((ext_vector_type(16))) float f32x16;
typedef __attribute__((ext_vector_type(4))) unsigned short u16x4;
typedef __attribute__((ext_vector_type(8))) unsigned short u16x8;
typedef __attribute__((ext_vector_type(2))) unsigned u32x2;

// RNE float -> bf16 bits
DEV unsigned short f2bf(float f) {
  unsigned u = __builtin_bit_cast(unsigned, f);
  u += 0x7FFFu + ((u >> 16) & 1u);
  return (unsigned short)(u >> 16);
}

DEV f32x4 mfma16(bf16x8 a, bf16x8 b, f32x4 c) {
  return __builtin_amdgcn_mfma_f32_16x16x32_bf16(a, b, c, 0, 0, 0);
}
DEV f32x16 mfma32(bf16x8 a, bf16x8 b, f32x16 c) {
  return __builtin_amdgcn_mfma_f32_32x32x16_bf16(a, b, c, 0, 0, 0);
}

// async global->LDS, 16B per lane; LDS dest must be wave-uniform base + lane*16
DEV void gload16(const void* g, void* l) {
  __builtin_amdgcn_global_load_lds(
      (const __attribute__((address_space(1))) unsigned int*)g,
      (__attribute__((address_space(3))) unsigned int*)l, 16, 0, 0);
}

// v_permlane32_swap_b32 (T12 primitive); semantics validated in R5/R6.
DEV void plswap(unsigned& x, unsigned& y) {
#if __has_builtin(__builtin_amdgcn_permlane32_swap)
  u32x2 r = __builtin_amdgcn_permlane32_swap(x, y, false, false);
  x = r[0];
  y = r[1];
#else
  unsigned sx = __shfl_xor(x, 32, 64), sy = __shfl_xor(y, 32, 64);
  int hi = (threadIdx.x & 63) >> 5;
  unsigned nx = hi ? sy : x;
  unsigned ny = hi ? y : sx;
  x = nx;
  y = ny;
#endif
}
DEV float xadd32(float v) {
  unsigned a = __builtin_bit_cast(unsigned, v), b = a;
  plswap(a, b);
  return __builtin_bit_cast(float, a) + __builtin_bit_cast(float, b);
}

// ---------------------------------------------------------------------------
// Fused fp32 -> bf16 swizzled convert for x + 4 weight matrices.
// ---------------------------------------------------------------------------
__global__ __launch_bounds__(256) void k_cvt_all(
    const float* __restrict__ x,
    const float* __restrict__ Wq, const float* __restrict__ Wk,
    const float* __restrict__ Wv, const float* __restrict__ Wo,
    unsigned short* __restrict__ xb,
    unsigned short* __restrict__ Wqb, unsigned short* __restrict__ Wkb,
    unsigned short* __restrict__ Wvb, unsigned short* __restrict__ Wob) {
  int g = blockIdx.x * 256 + threadIdx.x;
  const float* src;
  unsigned short* dst;
  int loc;
  if (g < 524288) {
    src = x; dst = xb; loc = g;
  } else {
    int r = g - 524288;
    int w = r >> 17;
    loc = r & 131071;
    src = w == 0 ? Wq : w == 1 ? Wk : w == 2 ? Wv : Wo;
    dst = w == 0 ? Wqb : w == 1 ? Wkb : w == 2 ? Wvb : Wob;
  }
  int row = loc >> 7, k8 = loc & 127;
  const f32x4* s = (const f32x4*)(src + ((size_t)row << 10) + (k8 << 3));
  f32x4 a = s[0], b = s[1];
  u16x8 o;
  o[0] = f2bf(a[0]); o[1] = f2bf(a[1]); o[2] = f2bf(a[2]); o[3] = f2bf(a[3]);
  o[4] = f2bf(b[0]); o[5] = f2bf(b[1]); o[6] = f2bf(b[2]); o[7] = f2bf(b[3]);
  *(u16x8*)(dst + ((size_t)row << 10) + ((k8 << 3) ^ ((row & 7) << 3))) = o;
}

// ---------------------------------------------------------------------------
// NT-GEMM mainloop: dbuf + counted vmcnt (validated R15).
// ---------------------------------------------------------------------------
DEV void gemm_mainloop(const char* Ag, const char* Bg, char* lds,
                       int lane, int wid, f32x4 acc[4][4]) {
  int g4 = lane >> 4, r16 = lane & 15;
  int wm = wid >> 1, wn = wid & 1;
  int adA[2], adB[2];
#pragma unroll
  for (int ks = 0; ks < 2; ++ks) {
    int swz = ((ks * 4 + g4) ^ (lane & 7)) << 4;
    adA[ks] = (wm * 64 + r16) * 128 + swz;
    adB[ks] = 16384 + (wn * 64 + r16) * 128 + swz;
  }
  int o0 = wid * 4096 + lane * 16;
  int grow[4], ginr[4];
#pragma unroll
  for (int i = 0; i < 4; ++i) {
    grow[i] = (o0 + i * 1024) >> 7;
    ginr[i] = (o0 + i * 1024) & 127;
  }
  auto STAGE = [&](int KT, int BASE) {
#pragma unroll
    for (int i = 0; i < 4; ++i) {
      int oo = o0 + i * 1024;
      size_t gofs = (size_t)grow[i] * 2048 + (size_t)KT * 128 + ginr[i];
      gload16(Ag + gofs, lds + BASE + oo);
      gload16(Bg + gofs, lds + BASE + 16384 + oo);
    }
  };
  STAGE(0, 0);
  for (int kt = 0; kt < 16; ++kt) {
    int cur = (kt & 1) << 15;
    if (kt + 1 < 16) {
      STAGE(kt + 1, cur ^ 32768);                      // flies across barrier
      asm volatile("s_waitcnt vmcnt(8)" ::: "memory"); // tile-kt landed
    } else {
      asm volatile("s_waitcnt vmcnt(0)" ::: "memory");
    }
    __builtin_amdgcn_s_barrier();       // all waves' tile-kt loads landed
    __builtin_amdgcn_sched_barrier(0);  // no hoist of ds_read above (rule 18)
#pragma unroll
    for (int ks = 0; ks < 2; ++ks) {
      bf16x8 af[4], bfr[4];
#pragma unroll
      for (int i = 0; i < 4; ++i) {
        af[i]  = *(const bf16x8*)(lds + cur + adA[ks] + i * 2048);
        bfr[i] = *(const bf16x8*)(lds + cur + adB[ks] + i * 2048);
      }
      __builtin_amdgcn_s_setprio(1);
#pragma unroll
      for (int mi = 0; mi < 4; ++mi)
#pragma unroll
        for (int ni = 0; ni < 4; ++ni)
          acc[mi][ni] = mfma16(af[mi], bfr[ni], acc[mi][ni]);
      __builtin_amdgcn_s_setprio(0);
    }
    asm volatile("s_waitcnt lgkmcnt(0)" ::: "memory");  // ds_reads drained
    __builtin_amdgcn_sched_barrier(0);
    __builtin_amdgcn_s_barrier();       // safe to overwrite other buf next iter
  }
}

// ---------------------------------------------------------------------------
// QKV projection: Q,K row-major [bh][s][64]; V transposed [bh][hd][s].
// Q is PRE-SCALED by 0.125*log2(e) so attention computes exp2(s) directly.
// ---------------------------------------------------------------------------
__global__ __launch_bounds__(256) void k_gemm_qkv(
    const unsigned short* __restrict__ xb,
    const unsigned short* __restrict__ Wqb, const unsigned short* __restrict__ Wkb,
    const unsigned short* __restrict__ Wvb,
    const float* __restrict__ bq, const float* __restrict__ bk,
    const float* __restrict__ bv,
    unsigned short* __restrict__ Qb, unsigned short* __restrict__ Kb,
    unsigned short* __restrict__ Vt) {
  __shared__ char lds[65536];
  int tid = threadIdx.x, lane = tid & 63, wid = tid >> 6;
  int bm = blockIdx.x & 31, bn = blockIdx.x >> 5;
  int r0 = bm * 128;
  int colT = bn * 128;
  int which = colT >> 10;
  int ncol = colT & 1023;
  const unsigned short* Wb = which == 0 ? Wqb : which == 1 ? Wkb : Wvb;
  f32x4 acc[4][4] = {};
  gemm_mainloop((const char*)xb + (size_t)r0 * 2048,
                (const char*)Wb + (size_t)ncol * 2048, lds, lane, wid, acc);
  int g4 = lane >> 4, r16 = lane & 15, wm = wid >> 1, wn = wid & 1;
  const float* bias = which == 0 ? bq : which == 1 ? bk : bv;
  float oscale = which == 0 ? 0.18033688f : 1.0f;  // Q pre-scale: 0.125*log2e
  int ncolw = ncol + wn * 64;
#pragma unroll
  for (int ni = 0; ni < 4; ++ni) {
    int gcol = ncolw + ni * 16 + r16;
    float bvv = bias[gcol];
    int h = gcol >> 6, hd = gcol & 63;
#pragma unroll
    for (int mi = 0; mi < 4; ++mi) {
      int growb = r0 + wm * 64 + mi * 16 + g4 * 4;
      int bb = growb >> 11, s0 = growb & 2047;
      if (which == 2) {
        u16x4 pk;
#pragma unroll
        for (int jj = 0; jj < 4; ++jj) pk[jj] = f2bf(acc[mi][ni][jj] + bvv);
        *(u16x4*)(Vt + ((size_t)(bb * 16 + h) * 64 + hd) * 2048 + s0) = pk;
      } else {
        unsigned short* dst = which == 0 ? Qb : Kb;
        size_t base = ((size_t)(bb * 16 + h) * 2048 + s0) * 64 + hd;
#pragma unroll
        for (int jj = 0; jj < 4; ++jj)
          dst[base + (size_t)jj * 64] = f2bf((acc[mi][ni][jj] + bvv) * oscale);
      }
    }
  }
}

// ---------------------------------------------------------------------------
// Flash attention, causal — R13 split-K/TLP structure + R15's counted-vmcnt
// DOUBLE BUFFER: per tile {STAGE(t+1, other buf) -> vmcnt(8) -> s_barrier ->
// compute(t) -> lgkmcnt(0) -> s_barrier}. Next tile's 8 loads fly under
// compute. LDS exactly 32768 B (finalize strip reuses dead K/V buffer after
// a __syncthreads) -> 5 blocks/CU. Segment table / no-max softmax unchanged.
// ---------------------------------------------------------------------------
__global__ __launch_bounds__(128) void k_attn(
    const unsigned short* __restrict__ Q, const unsigned short* __restrict__ K,
    const unsigned short* __restrict__ Vt, unsigned short* __restrict__ ansb,
    float* __restrict__ PO, float* __restrict__ PL) {
  __shared__ char lds[2 * 16384];
  // entry: c | t0<<8 | t1<<16 | j<<24, ordered by descending (t1-t0)
#define SG(c, a, bb2, jj) \
  ((unsigned)(c) | ((unsigned)(a) << 8) | ((unsigned)(bb2) << 16) | ((unsigned)(jj) << 24))
  static const unsigned SEGT[80] = {
    // length 8 (20)
    SG(31,0,8,0),  SG(31,8,16,1), SG(31,16,24,2), SG(31,24,32,3),
    SG(30,7,15,1), SG(30,15,23,2), SG(30,23,31,3),
    SG(29,7,15,1), SG(29,22,30,3), SG(28,21,29,3),
    SG(23,0,8,0),  SG(23,8,16,1), SG(23,16,24,2),
    SG(22,7,15,1), SG(22,15,23,2), SG(21,14,22,2),
    SG(15,0,8,0),  SG(15,8,16,1), SG(14,7,15,1),  SG(7,0,8,0),
    // length 7 (30)
    SG(30,0,7,0),  SG(29,0,7,0),  SG(29,15,22,2),
    SG(28,0,7,0),  SG(28,7,14,1), SG(28,14,21,2),
    SG(27,0,7,0),  SG(27,7,14,1), SG(27,14,21,2), SG(27,21,28,3),
    SG(26,6,13,1), SG(26,13,20,2), SG(26,20,27,3),
    SG(25,6,13,1), SG(25,19,26,3), SG(24,18,25,3),
    SG(22,0,7,0),  SG(21,0,7,0),  SG(21,7,14,1),
    SG(20,0,7,0),  SG(20,7,14,1), SG(20,14,21,2),
    SG(19,6,13,1), SG(19,13,20,2), SG(18,12,19,2),
    SG(14,0,7,0),  SG(13,0,7,0),  SG(13,7,14,1),
    SG(12,6,13,1), SG(6,0,7,0),
    // length 6 (19)
    SG(26,0,6,0),  SG(25,0,6,0),  SG(25,13,19,2),
    SG(24,0,6,0),  SG(24,6,12,1), SG(24,12,18,2),
    SG(19,0,6,0),  SG(18,0,6,0),  SG(18,6,12,1),
    SG(17,0,6,0),  SG(17,6,12,1), SG(17,12,18,2),
    SG(16,5,11,1), SG(16,11,17,2),
    SG(12,0,6,0),  SG(11,0,6,0),  SG(11,6,12,1),
    SG(10,5,11,1), SG(5,0,6,0),
    // length 5 (6)
    SG(16,0,5,0), SG(10,0,5,0), SG(9,0,5,0), SG(9,5,10,1), SG(8,4,9,1),
    SG(4,0,5,0),
    // tails (4)
    SG(8,0,4,0), SG(3,0,4,0), SG(2,0,3,0), SG(1,0,2,0), SG(0,0,1,0)
  };
#undef SG
  int tid = threadIdx.x, lane = tid & 63, wid = tid >> 6;  // wid 0..1
  int l31 = lane & 31, hi = lane >> 5;
  int bid = blockIdx.x;
  int bh = (bid & 7) * 4 + ((bid >> 3) & 3);  // same bh -> same XCD (mod-8 rr)
  unsigned se = SEGT[bid >> 5];
  int c = se & 255, t0 = (se >> 8) & 255, t1 = (se >> 16) & 255, j = se >> 24;
  bool direct = (c < 8);                       // nseg==1 chunks
  int pidx = (bh * 24 + (c - 8)) * 4 + j;      // valid only when !direct
  int b = bh >> 4, h = bh & 15;
  int q0 = c * 64 + wid * 32;       // this wave's q-row base
  const unsigned short* Qh = Q + (size_t)bh * (2048 * 64);
  const char* Kg = (const char*)(K + (size_t)bh * (2048 * 64));
  const char* Vg = (const char*)(Vt + (size_t)bh * (64 * 2048));

  // staging offsets (128 threads, 8KB K + 8KB V -> 4+4 gload16 per thread)
  int kof[4], ko[4], vo[4];
#pragma unroll
  for (int i = 0; i < 4; ++i) {
    int o = tid * 16 + i * 2048;
    int row = o >> 7, cc = o & 127;
    int sc = cc ^ ((row & 7) << 4);
    kof[i] = o;
    ko[i] = row * 128 + sc;    // K rows = kv (row stride 128B)
    vo[i] = row * 4096 + sc;   // V rows = hd (row stride 4096B)
  }

  // Q fragments (B-operand): col=lane&31=q, k=(lane>>5)*8+jj per 16-k step
  bf16x8 qf[4];
#pragma unroll
  for (int ks = 0; ks < 4; ++ks)
    qf[ks] = *(const bf16x8*)(Qh + (size_t)(q0 + l31) * 64 + ks * 16 + hi * 8);

  f32x16 O0 = {}, O1 = {}, l16 = {};
  int swzl = (l31 & 7) << 4;
  int hioff = hi * 16;

  auto STAGEA = [&](int T, int BASE) {
    size_t kK = (size_t)T * 8192;   // K tile byte offset (64 rows x 128B)
    size_t kV = (size_t)T * 128;    // V tile byte offset (64 kv x 2B per row)
#pragma unroll
    for (int i = 0; i < 4; ++i) {
      gload16(Kg + kK + ko[i], lds + BASE + kof[i]);
      gload16(Vg + kV + vo[i], lds + BASE + 8192 + kof[i]);
    }
  };

  STAGEA(t0, 0);
  for (int t = t0; t < t1; ++t) {
    int cur = ((t - t0) & 1) << 14;
    if (t + 1 < t1) {
      STAGEA(t + 1, cur ^ 16384);                       // flies across barrier
      asm volatile("s_waitcnt vmcnt(8)" ::: "memory");  // tile-t landed
    } else {
      asm volatile("s_waitcnt vmcnt(0)" ::: "memory");
    }
    __builtin_amdgcn_s_barrier();        // all waves' tile-t loads landed
    __builtin_amdgcn_sched_barrier(0);   // no hoist of ds_read above (rule 18)
    const char* KL = lds + cur;
    const char* VL = KL + 8192;
    f32x16 s0 = {}, s1 = {};
    __builtin_amdgcn_s_setprio(1);
#pragma unroll
    for (int ks = 0; ks < 4; ++ks) {
      bf16x8 kf0 = *(const bf16x8*)(KL + l31 * 128 + ((ks * 32 + hioff) ^ swzl));
      bf16x8 kf1 = *(const bf16x8*)(KL + (32 + l31) * 128 + ((ks * 32 + hioff) ^ swzl));
      s0 = mfma32(kf0, qf[ks], s0);
      s1 = mfma32(kf1, qf[ks], s1);
    }
    __builtin_amdgcn_s_setprio(0);
    if (t == c) {  // diagonal tile: causal mask
      int lim2 = q0 + l31 - t * 64 - 4 * hi;
#pragma unroll
      for (int r = 0; r < 16; ++r) {
        int kc = (r & 3) + 8 * (r >> 2);
        if (kc > lim2) s0[r] = -1e30f;
        if (kc + 32 > lim2) s1[r] = -1e30f;
      }
    }
    // P = exp2(s) (Q pre-scaled; masked -1e30 -> 0); per-lane partial l
#pragma unroll
    for (int r = 0; r < 16; ++r) {
      s0[r] = __builtin_amdgcn_exp2f(s0[r]);
      s1[r] = __builtin_amdgcn_exp2f(s1[r]);
      l16[r] += s0[r] + s1[r];
    }
    // pack P->bf16 A-frags: cvt_pk pairs + permlane32_swap
    __builtin_amdgcn_s_setprio(1);
#define PV_CHUNK(SV, E, C16) { \
    unsigned x0, x1, y0, y1; \
    asm("v_cvt_pk_bf16_f32 %0, %1, %2" : "=v"(x0) : "v"(SV[8*(E)+0]), "v"(SV[8*(E)+1])); \
    asm("v_cvt_pk_bf16_f32 %0, %1, %2" : "=v"(x1) : "v"(SV[8*(E)+2]), "v"(SV[8*(E)+3])); \
    asm("v_cvt_pk_bf16_f32 %0, %1, %2" : "=v"(y0) : "v"(SV[8*(E)+4]), "v"(SV[8*(E)+5])); \
    asm("v_cvt_pk_bf16_f32 %0, %1, %2" : "=v"(y1) : "v"(SV[8*(E)+6]), "v"(SV[8*(E)+7])); \
    plswap(x0, y0); \
    plswap(x1, y1); \
    union { unsigned u[4]; bf16x8 v; } pf; \
    pf.u[0] = x0; \
    pf.u[1] = x1; \
    pf.u[2] = y0; \
    pf.u[3] = y1; \
    bf16x8 v0 = *(const bf16x8*)(VL + l31 * 128 + (((C16) * 32 + hioff) ^ swzl)); \
    bf16x8 v1 = *(const bf16x8*)(VL + (32 + l31) * 128 + (((C16) * 32 + hioff) ^ swzl)); \
    O0 = mfma32(pf.v, v0, O0); \
    O1 = mfma32(pf.v, v1, O1); }
    PV_CHUNK(s0, 0, 0)
    PV_CHUNK(s0, 1, 1)
    PV_CHUNK(s1, 0, 2)
    PV_CHUNK(s1, 1, 3)
#undef PV_CHUNK
    __builtin_amdgcn_s_setprio(0);
    asm volatile("s_waitcnt lgkmcnt(0)" ::: "memory");  // my ds_reads drained
    __builtin_amdgcn_sched_barrier(0);
    __builtin_amdgcn_s_barrier();   // all waves done reading buf before reuse
  }
  // row-sum of l (tree + single cross-half reduce) -> lf per q-row (=l31)
  float a[16];
#pragma unroll
  for (int r = 0; r < 16; ++r) a[r] = l16[r];
#pragma unroll
  for (int st2 = 8; st2 >= 1; st2 >>= 1)
#pragma unroll
    for (int i = 0; i < st2; ++i) a[i] += a[i + st2];
  float lf = xadd32(a[0]);
  __syncthreads();  // K/V buffers dead on all waves; strip reuse safe
  char* wb = lds + wid * 128;  // per-wave broadcast strip (reuses buffer 0)
  if (direct) {
    float rl = 1.f / lf;
    if (lane < 32) *(float*)(wb + l31 * 4) = rl;
    asm volatile("s_waitcnt lgkmcnt(0)" ::: "memory");
    f32x4 rv0 = *(const f32x4*)(wb + hioff);
    f32x4 rv1 = *(const f32x4*)(wb + 32 + hioff);
    f32x4 rv2 = *(const f32x4*)(wb + 64 + hioff);
    f32x4 rv3 = *(const f32x4*)(wb + 96 + hioff);
#pragma unroll
    for (int r = 0; r < 16; ++r) {
      float sc = (r < 4 ? rv0 : r < 8 ? rv1 : r < 12 ? rv2 : rv3)[r & 3];
      int rowl = q0 + (r & 3) + 8 * (r >> 2) + 4 * hi;
      int rowg = (b << 11) + rowl;
      int cswz = (rowl & 7) << 3;
      int cg0 = (h << 6) + l31;
      int cg1 = (h << 6) + 32 + l31;
      ansb[(size_t)rowg * 1024 + (cg0 ^ cswz)] = f2bf(O0[r] * sc);
      ansb[(size_t)rowg * 1024 + (cg1 ^ cswz)] = f2bf(O1[r] * sc);
    }
  } else {
    float* po = PO + (size_t)pidx * 4096;
#pragma unroll
    for (int r = 0; r < 16; ++r) {
      int rowl = wid * 32 + (r & 3) + 8 * (r >> 2) + 4 * hi;  // 0..63
      po[rowl * 64 + l31] = O0[r];
      po[rowl * 64 + 32 + l31] = O1[r];
    }
    if (hi == 0) PL[pidx * 64 + wid * 32 + l31] = lf;
  }
}

// ---------------------------------------------------------------------------
// Split-K combine: for (bh, chunk 8..31) sum nseg partials, normalize, write
// swizzled bf16 ansb. Grid 768 = 32 bh x 24 chunks; 256 thr.
// ---------------------------------------------------------------------------
__global__ __launch_bounds__(256) void k_attn_combine(
    const float* __restrict__ PO, const float* __restrict__ PL,
    unsigned short* __restrict__ ansb) {
  int bid = blockIdx.x;
  int bh = bid & 31, cc = 8 + (bid >> 5);
  int nseg = cc < 16 ? 2 : cc < 24 ? 3 : 4;
  int b = bh >> 4, h = bh & 15;
  int t = threadIdx.x;
  int r = t >> 2, c4 = (t & 3) << 4;
  int pbase = (bh * 24 + (cc - 8)) * 4;
  f32x4 s0 = {}, s1 = {}, s2 = {}, s3 = {};
  float lsum = 0.f;
  for (int j = 0; j < nseg; ++j) {
    const float* A = PO + (size_t)(pbase + j) * 4096 + r * 64 + c4;
    s0 += *(const f32x4*)(A + 0);
    s1 += *(const f32x4*)(A + 4);
    s2 += *(const f32x4*)(A + 8);
    s3 += *(const f32x4*)(A + 12);
    lsum += PL[(pbase + j) * 64 + r];
  }
  float rl = 1.f / lsum;
  u16x8 o0, o1;
#pragma unroll
  for (int j = 0; j < 4; ++j) {
    o0[j] = f2bf(s0[j] * rl);
    o0[4 + j] = f2bf(s1[j] * rl);
    o1[j] = f2bf(s2[j] * rl);
    o1[4 + j] = f2bf(s3[j] * rl);
  }
  int rowg = (b << 11) + cc * 64 + r;
  int colg = (h << 6) + c4;
  int cswz = (rowg & 7) << 3;
  *(u16x8*)(ansb + (size_t)rowg * 1024 + (colg ^ cswz)) = o0;
  *(u16x8*)(ansb + (size_t)rowg * 1024 + ((colg + 8) ^ cswz)) = o1;
}

// ---------------------------------------------------------------------------
// Output projection: out(fp32) = ansb(swz) * Wo^T + bo. Grid 256 = 1 block/CU
// -> counted-vmcnt dbuf mainloop (ILP is the only hiding at this grid).
// ---------------------------------------------------------------------------
__global__ __launch_bounds__(256) void k_gemm_out(
    const unsigned short* __restrict__ ansb, const unsigned short* __restrict__ Wob,
    const float* __restrict__ bo, float* __restrict__ out) {
  __shared__ char lds[65536];
  int tid = threadIdx.x, lane = tid & 63, wid = tid >> 6;
  int bm = blockIdx.x & 31, bn = blockIdx.x >> 5;
  int r0 = bm * 128, c0 = bn * 128;
  f32x4 acc[4][4] = {};
  gemm_mainloop((const char*)ansb + (size_t)r0 * 2048,
                (const char*)Wob + (size_t)c0 * 2048, lds, lane, wid, acc);
  int g4 = lane >> 4, r16 = lane & 15, wm = wid >> 1, wn = wid & 1;
#pragma unroll
  for (int ni = 0; ni < 4; ++ni) {
    int gcol = c0 + wn * 64 + ni * 16 + r16;
    float bvv = bo[gcol];
#pragma unroll
    for (int mi = 0; mi < 4; ++mi) {
      int growb = r0 + wm * 64 + mi * 16 + g4 * 4;
#pragma unroll
      for (int jj = 0; jj < 4; ++jj)
        out[(size_t)(growb + jj) * 1024 + gcol] = acc[mi][ni][jj] + bvv;
    }
  }
}

extern "C" void kernel_launch(void* const* d_in, const int* in_sizes, int n_in,
                              void* d_out, int out_size, void* d_ws, size_t ws_size,
                              hipStream_t stream) {
  const float* x  = (const float*)d_in[0];
  const float* Wq = (const float*)d_in[1];
  const float* bq = (const float*)d_in[2];
  const float* Wk = (const float*)d_in[3];
  const float* bk = (const float*)d_in[4];
  const float* Wv = (const float*)d_in[5];
  const float* bv = (const float*)d_in[6];
  const float* Wo = (const float*)d_in[7];
  const float* bo = (const float*)d_in[8];
  char* ws = (char*)d_ws;
  unsigned short* xb   = (unsigned short*)(ws);                  // 8 MB
  unsigned short* ansb = (unsigned short*)(ws);                  // 8 MB (alias, xb dead)
  unsigned short* Wqb  = (unsigned short*)(ws + (8u  << 20));
  unsigned short* Wkb  = (unsigned short*)(ws + (10u << 20));
  unsigned short* Wvb  = (unsigned short*)(ws + (12u << 20));
  unsigned short* Wob  = (unsigned short*)(ws + (14u << 20));
  unsigned short* Qb   = (unsigned short*)(ws + (16u << 20));
  unsigned short* Kb   = (unsigned short*)(ws + (24u << 20));
  unsigned short* Vt   = (unsigned short*)(ws + (32u << 20));
  float*          PO   = (float*)(ws + (40u << 20));             // 48 MB (3072 x 16KB)
  float*          PL   = (float*)(ws + (88u << 20));             // 768 KB

  k_cvt_all<<<4096, 256, 0, stream>>>(x, Wq, Wk, Wv, Wo, xb, Wqb, Wkb, Wvb, Wob);
  k_gemm_qkv<<<768, 256, 0, stream>>>(xb, Wqb, Wkb, Wvb, bq, bk, bv, Qb, Kb, Vt);
  k_attn<<<2560, 128, 0, stream>>>(Qb, Kb, Vt, ansb, PO, PL);
  k_attn_combine<<<768, 256, 0, stream>>>(PO, PL, ansb);
  k_gemm_out<<<256, 256, 0, stream>>>(ansb, Wob, bo, (float*)d_out);
}